// Round 1
// baseline (67.729 us; speedup 1.0000x reference)
//
#include <hip/hip_runtime.h>

#define NQ 5
#define NL 6
#define NG 4
#define DIM 32          // 2^NQ
#define PATCH 16        // 2^(NQ-1)
#define WTOT (NG*NL*NQ) // 120 weight angles

// CZ-chain sign: flip amplitude i iff the number of adjacent set-bit pairs
// in (q0..q4) is odd. i = q0*16+q1*8+q2*4+q3*2+q4, so adjacent wire pairs
// are adjacent bit pairs of i.
__device__ __forceinline__ int flip_par(int i) {
    int p = i & (i >> 1) & 0xF;
    p ^= p >> 2;
    p ^= p >> 1;
    return p & 1;
}

__global__ __launch_bounds__(256) void qgen_kernel(
        const float* __restrict__ x, const float* __restrict__ qp,
        float* __restrict__ out, int B) {
    __shared__ float lc[WTOT];
    __shared__ float ls[WTOT];
    const float RV = 0.07957747154594767f; // 0.5 / (2*pi): v_sin/v_cos take revolutions

    const int t = threadIdx.x;
    if (t < WTOT) {
        float h = qp[t] * RV;
        lc[t] = __builtin_amdgcn_cosf(h);
        ls[t] = __builtin_amdgcn_sinf(h);
    }
    __syncthreads();

    const int b = blockIdx.x * blockDim.x + t;
    if (b >= B) return;

    // --- noise angles: cos/sin of x/2 ---
    float cn[NQ], sn[NQ];
    #pragma unroll
    for (int w = 0; w < NQ; ++w) {
        float h = x[(size_t)b * NQ + w] * RV;
        cn[w] = __builtin_amdgcn_cosf(h);
        sn[w] = __builtin_amdgcn_sinf(h);
    }

    // --- product state from noise RYs on |00000> (shared across generators) ---
    float base[DIM];
    base[0] = cn[0]; base[1] = sn[0];
    #pragma unroll
    for (int w = 1; w < NQ; ++w) {
        #pragma unroll
        for (int j = (1 << w) - 1; j >= 0; --j) {
            float v = base[j];
            base[2*j + 1] = v * sn[w];
            base[2*j]     = v * cn[w];
        }
    }

    float* og = out + (size_t)b * (NG * PATCH);

    #pragma unroll 1
    for (int g = 0; g < NG; ++g) {
        float st[DIM];
        #pragma unroll
        for (int i = 0; i < DIM; ++i) st[i] = base[i];

        const int woff = g * (NL * NQ);
        #pragma unroll 1
        for (int l = 0; l < NL; ++l) {
            #pragma unroll
            for (int w = 0; w < NQ; ++w) {
                float c = lc[woff + l*NQ + w];
                float s = ls[woff + l*NQ + w];
                const int bit = 4 - w;       // wire w acts on bit (4-w) of i
                const int str = 1 << bit;
                #pragma unroll
                for (int p = 0; p < 16; ++p) {
                    int lo = ((p >> bit) << (bit + 1)) | (p & (str - 1));
                    int hi = lo + str;
                    float a0 = st[lo], a1 = st[hi];
                    st[lo] = c*a0 - s*a1;
                    st[hi] = s*a0 + c*a1;
                }
            }
            if (l != NL - 1) {               // last layer's sign dies in |.|^2
                #pragma unroll
                for (int i = 0; i < DIM; ++i)
                    if (flip_par(i)) st[i] = -st[i];
            }
        }

        // out = p[:16] / max(p[:16])  (sum normalization cancels)
        float p0[PATCH];
        #pragma unroll
        for (int i = 0; i < PATCH; ++i) p0[i] = st[i] * st[i];
        float mx = p0[0];
        #pragma unroll
        for (int i = 1; i < PATCH; ++i) mx = fmaxf(mx, p0[i]);
        float inv = __builtin_amdgcn_rcpf(mx);
        #pragma unroll
        for (int i = 0; i < PATCH; ++i) p0[i] *= inv;

        float4* o4 = (float4*)(og + g * PATCH);
        #pragma unroll
        for (int k = 0; k < 4; ++k)
            o4[k] = make_float4(p0[4*k], p0[4*k+1], p0[4*k+2], p0[4*k+3]);
    }
}

extern "C" void kernel_launch(void* const* d_in, const int* in_sizes, int n_in,
                              void* d_out, int out_size, void* d_ws, size_t ws_size,
                              hipStream_t stream) {
    const float* x  = (const float*)d_in[0];
    const float* qp = (const float*)d_in[1];
    float* out = (float*)d_out;
    const int B = in_sizes[0] / NQ;
    dim3 block(256);
    dim3 grid((B + 255) / 256);
    qgen_kernel<<<grid, block, 0, stream>>>(x, qp, out, B);
}